// Round 22
// baseline (113.381 us; speedup 1.0000x reference)
//
#include <hip/hip_runtime.h>

typedef unsigned short u16;
typedef unsigned int u32;
typedef __attribute__((ext_vector_type(8))) short bf16x8;
typedef __attribute__((ext_vector_type(4))) float f32x4;
typedef __attribute__((ext_vector_type(16))) float f32x16;
typedef __attribute__((ext_vector_type(4))) u32 u32x4;

#define MFMA16(a, b, c) __builtin_amdgcn_mfma_f32_16x16x32_bf16((a), (b), (c), 0, 0, 0)
#define MFMA32(a, b, c) __builtin_amdgcn_mfma_f32_32x32x16_bf16((a), (b), (c), 0, 0, 0)

__device__ __forceinline__ void async_lds16(void* lds, const void* g) {
  __builtin_amdgcn_global_load_lds(
      (const __attribute__((address_space(1))) void*)g,
      (__attribute__((address_space(3))) void*)lds, 16, 0, 0);
}

__device__ __forceinline__ u16 f2bf(float f) {
  union { float f; unsigned u; } v; v.f = f;
  unsigned r = v.u + 0x7fffu + ((v.u >> 16) & 1u);
  return (u16)(r >> 16);
}

__device__ __forceinline__ u32 cvt_pk_bf16(float lo, float hi) {
  u32 r;
  asm("v_cvt_pk_bf16_f32 %0, %1, %2" : "=v"(r) : "v"(lo), "v"(hi));
  return r;
}

__device__ __forceinline__ float exp2_fast(float x) {
  float r;
  asm("v_exp_f32 %0, %1" : "=v"(r) : "v"(x));
  return r;
}

// swaps a's hi-32 lanes with b's lo-32 lanes
__device__ __forceinline__ void pswap(u32& a, u32& b) {
  asm("v_permlane32_swap_b32 %0, %1" : "+v"(a), "+v"(b));
}

// ---------------- fused preprocess kernel ----------------
// blocks [0,4096): f32->bf16 cvt of x; [4096,7168): w_qkv transpose (96x32);
// [7168,8192): w_out transpose (32x32).

__device__ __forceinline__ void transpose_cvt_body(const float* __restrict__ in, u16* __restrict__ out,
                                                   int R, int C, int bx, int by,
                                                   float (*tile)[33]) {
  int c0 = bx * 32, r0 = by * 32;
  int tx = threadIdx.x & 31, ty = threadIdx.x >> 5;
#pragma unroll
  for (int i = 0; i < 32; i += 8)
    tile[ty + i][tx] = in[(long)(r0 + ty + i) * C + c0 + tx];
  __syncthreads();
#pragma unroll
  for (int i = 0; i < 32; i += 8)
    out[(long)(c0 + ty + i) * R + r0 + tx] = f2bf(tile[tx][ty + i]);
}

__global__ __launch_bounds__(256) void k_prep(const float* __restrict__ x, u16* __restrict__ xb,
                                              const float* __restrict__ w_qkv, u16* __restrict__ wqkvT,
                                              const float* __restrict__ w_out, u16* __restrict__ woutT) {
  __shared__ float tile[32][33];
  const int B = blockIdx.x;
  if (B < 4096) {
    int i = (B * 256 + threadIdx.x) * 4;
    float4 v = *(const float4*)(x + i);
    ushort4 o;
    o.x = f2bf(v.x); o.y = f2bf(v.y); o.z = f2bf(v.z); o.w = f2bf(v.w);
    *(ushort4*)(xb + i) = o;
  } else if (B < 7168) {
    int bb = B - 4096;
    transpose_cvt_body(w_qkv, wqkvT, 1024, 3072, bb % 96, bb / 96, tile);
  } else {
    int bb = B - 7168;
    transpose_cvt_body(w_out, woutT, 1024, 1024, bb & 31, bb >> 5, tile);
  }
}

// ---------------- NT GEMM core (counted-vmcnt single-barrier pipeline) ----------------

template <int BM, int BN, int NW, int WN, int WCS, int MR, int NR, int NLD>
__device__ __forceinline__ void gemm_core_pipe(const u16* __restrict__ A, const u16* __restrict__ Bt,
                                               int K, long row0, long col0,
                                               u16* sA, u16* sB, f32x4 (&acc)[MR][NR]) {
  const int NTHR = NW * 64;
  const int ABYTES = BM * 64 * 2;
  const int BBYTES = BN * 64 * 2;
  const int t = threadIdx.x;
  const int lane = t & 63, g = lane >> 4, m16 = lane & 15;
  const int wid = t >> 6, wr = wid / WN, wc = wid % WN;
  const int nkt = K >> 6;

  auto stage = [&](int buf, int kt) {
    const int k0 = kt << 6;
#pragma unroll
    for (int it = 0; it < ABYTES / (NTHR * 16); ++it) {
      int i = it * NTHR + t;
      int r = i >> 3, c = i & 7, cs = c ^ (r & 7);
      async_lds16((char*)sA + buf * ABYTES + i * 16, A + (row0 + r) * K + k0 + cs * 8);
    }
#pragma unroll
    for (int it = 0; it < BBYTES / (NTHR * 16); ++it) {
      int i = it * NTHR + t;
      int r = i >> 3, c = i & 7, cs = c ^ (r & 7);
      async_lds16((char*)sB + buf * BBYTES + i * 16, Bt + (col0 + r) * K + k0 + cs * 8);
    }
  };

  stage(0, 0);
  stage(1, 1);
  int cur = 0;
  for (int kt = 0; kt < nkt; ++kt) {
    if (kt + 1 < nkt) {
      if constexpr (NLD == 7) asm volatile("s_waitcnt vmcnt(7)" ::: "memory");
      else                    asm volatile("s_waitcnt vmcnt(8)" ::: "memory");
    } else {
      asm volatile("s_waitcnt vmcnt(0)" ::: "memory");
    }
    __builtin_amdgcn_s_barrier();
    __builtin_amdgcn_sched_barrier(0);
    const char* bA = (const char*)sA + cur * ABYTES;
    const char* bB = (const char*)sB + cur * BBYTES;
#pragma unroll
    for (int kk6 = 0; kk6 < 2; ++kk6) {
      const int ke = kk6 * 32 + 8 * g;
      bf16x8 av[MR], bv[NR];
#pragma unroll
      for (int mi = 0; mi < MR; ++mi) {
        int row = wr * (MR * 16) + mi * 16 + m16;
        av[mi] = *(const bf16x8*)(bA + (row << 7) + ((ke << 1) ^ ((row & 7) << 4)));
      }
#pragma unroll
      for (int ni = 0; ni < NR; ++ni) {
        int row = wc * WCS + ni * 16 + m16;
        bv[ni] = *(const bf16x8*)(bB + (row << 7) + ((ke << 1) ^ ((row & 7) << 4)));
      }
#pragma unroll
      for (int mi = 0; mi < MR; ++mi)
#pragma unroll
        for (int ni = 0; ni < NR; ++ni)
          acc[mi][ni] = MFMA16(av[mi], bv[ni], acc[mi][ni]);
    }
    __builtin_amdgcn_sched_barrier(0);
    __builtin_amdgcn_s_barrier();
    if (kt + 2 < nkt) stage(cur, kt + 2);
    cur ^= 1;
  }
}

// GEMM1: xb[4096][1024] x wqkvT[3072][1024]^T, 256x192 tile, 512 thr (8 waves 2x4).
// Grid 256 = 1 block/CU; col0 = colt*192 -> block maps to head colt.
// V is written DIRECTLY in transposed layout Vt[bh][d][s].
__global__ __launch_bounds__(512, 2) void k_gemm_qkv(const u16* __restrict__ xb, const u16* __restrict__ wT,
                                                     u16* __restrict__ Qo, u16* __restrict__ Ko,
                                                     u16* __restrict__ Vt) {
  __shared__ __align__(16) u16 sA[2 * 256 * 64];  // 64KB
  __shared__ __align__(16) u16 sB[2 * 192 * 64];  // 48KB
  f32x4 acc[8][3];
  const f32x4 z = {0.f, 0.f, 0.f, 0.f};
#pragma unroll
  for (int mi = 0; mi < 8; ++mi)
#pragma unroll
    for (int ni = 0; ni < 3; ++ni) acc[mi][ni] = z;
  const int L = blockIdx.x;
  const int xcd = L & 7, idx = L >> 3;          // idx 0..31
  const int rowt = xcd * 2 + (idx & 1);         // 0..15
  const int colt = idx >> 1;                    // 0..15 (= head h)
  long row0 = (long)rowt * 256, col0 = (long)colt * 192;
  gemm_core_pipe<256, 192, 8, 4, 48, 8, 3, 7>(xb, wT, 1024, row0, col0, sA, sB, acc);
  const int t = threadIdx.x;
  const int lane = t & 63, g = lane >> 4, m16 = lane & 15;
  const int wid = t >> 6, wr = wid >> 2, wc = wid & 3;
  const int h = colt;
#pragma unroll
  for (int mi = 0; mi < 8; ++mi) {
#pragma unroll
    for (int ni = 0; ni < 3; ++ni) {
      int rem = wc * 48 + ni * 16 + m16;        // 0..191 within head
      int which = rem >> 6, d = rem & 63;
      int row_base = (int)row0 + wr * 128 + mi * 16 + 4 * g;  // multiple of 4
      int b = row_base >> 11, s = row_base & 2047;
      if (which == 2) {
        // Vt[bh][d][s..s+3]: contiguous, 8B-aligned
        ushort4 o;
        o.x = f2bf(acc[mi][ni][0]); o.y = f2bf(acc[mi][ni][1]);
        o.z = f2bf(acc[mi][ni][2]); o.w = f2bf(acc[mi][ni][3]);
        *(ushort4*)(Vt + ((long)(b * 16 + h)) * 131072 + (long)d * 2048 + s) = o;
      } else {
        long off = (((long)(b * 16 + h)) * 2048 + s) * 64 + d;
#pragma unroll
        for (int r = 0; r < 4; ++r) {
          float v = acc[mi][ni][r];
          if (which == 0) Qo[off + (long)r * 64] = f2bf(v * 0.18033688f);  // 0.125*log2e
          else            Ko[off + (long)r * 64] = f2bf(v);
        }
      }
    }
  }
}

// GEMM2: Ob[4096][1024] x woutT[1024][1024]^T -> out f32 [4096][1024]
__global__ __launch_bounds__(256) void k_gemm_out(const u16* __restrict__ Ob, const u16* __restrict__ wT,
                                                  float* __restrict__ out) {
  __shared__ __align__(16) u16 sA[2 * 128 * 64];  // 32KB
  __shared__ __align__(16) u16 sB[2 * 128 * 64];  // 32KB
  f32x4 acc[4][4];
  const f32x4 z = {0.f, 0.f, 0.f, 0.f};
#pragma unroll
  for (int mi = 0; mi < 4; ++mi)
#pragma unroll
    for (int ni = 0; ni < 4; ++ni) acc[mi][ni] = z;
  const int L = blockIdx.x;
  const int xcd = L & 7, idx = L >> 3;          // idx 0..31
  const int rowt = xcd * 4 + (idx & 3);         // 0..31
  const int colt = idx >> 2;                    // 0..7
  long row0 = (long)rowt * 128, col0 = (long)colt * 128;
  gemm_core_pipe<128, 128, 4, 2, 64, 4, 4, 8>(Ob, wT, 1024, row0, col0, sA, sB, acc);
  const int t = threadIdx.x;
  const int lane = t & 63, g = lane >> 4, m16 = lane & 15;
  const int wid = t >> 6, wr = wid >> 1, wc = wid & 1;
#pragma unroll
  for (int mi = 0; mi < 4; ++mi) {
#pragma unroll
    for (int ni = 0; ni < 4; ++ni) {
#pragma unroll
      for (int r = 0; r < 4; ++r) {
        long row = row0 + wr * 64 + mi * 16 + 4 * g + r;
        long col = col0 + wc * 64 + ni * 16 + m16;
        out[row * 1024 + col] = acc[mi][ni][r];
      }
    }
  }
}

// ---------------- causal flash attention: r19 math + SINGLE barrier per tile ----------------
// Block (bh, pr) = 256 thr = 4 waves; wave w owns heavy strip qtB*4+w and light
// strip qtA*4+w. 4 K/V buffers; prologue stages tiles 0-2 (3 in flight = 12 loads).
// Loop: vmcnt(rem>=3?8:rem==2?4:0) -> ONE raw barrier (frees buf (kt-1)&3) ->
// stage(kt+3) into that freed buffer -> compute. (Barrier scheme correctness-
// demonstrated by r20, which passed with this exact ordering.)

template <bool DIAG>
__device__ __forceinline__ void attn_sub(const char* Kt, const char* Vt, int bsub,
                                         bf16x8 qf0, bf16x8 qf1, bf16x8 qf2, bf16x8 qf3,
                                         f32x16& acc0, f32x16& acc1, float& l,
                                         int q5, int hi) {
  const int x7 = q5 & 7;
  const int rowK = (bsub * 32 + q5) << 7;
  bf16x8 k0 = *(const bf16x8*)(Kt + rowK + (((0 + hi) ^ x7) << 4));
  bf16x8 k1 = *(const bf16x8*)(Kt + rowK + (((2 + hi) ^ x7) << 4));
  bf16x8 k2 = *(const bf16x8*)(Kt + rowK + (((4 + hi) ^ x7) << 4));
  bf16x8 k3 = *(const bf16x8*)(Kt + rowK + (((6 + hi) ^ x7) << 4));
  const int rowV0 = q5 << 7, rowV1 = (q5 + 32) << 7;
  bf16x8 v00 = *(const bf16x8*)(Vt + rowV0 + (((bsub * 4 + 0 + hi) ^ x7) << 4));
  bf16x8 v01 = *(const bf16x8*)(Vt + rowV1 + (((bsub * 4 + 0 + hi) ^ x7) << 4));
  bf16x8 v10 = *(const bf16x8*)(Vt + rowV0 + (((bsub * 4 + 2 + hi) ^ x7) << 4));
  bf16x8 v11 = *(const bf16x8*)(Vt + rowV1 + (((bsub * 4 + 2 + hi) ^ x7) << 4));

  f32x16 s;
#pragma unroll
  for (int r = 0; r < 16; ++r) s[r] = 0.f;
  __builtin_amdgcn_s_setprio(1);
  s = MFMA32(k0, qf0, s);
  s = MFMA32(k1, qf1, s);
  s = MFMA32(k2, qf2, s);
  s = MFMA32(k3, qf3, s);
  __builtin_amdgcn_s_setprio(0);

  float p[16];
#pragma unroll
  for (int r = 0; r < 16; ++r) {
    float pv = exp2_fast(s[r]);
    if (DIAG) {
      int crow = (r & 3) + 8 * (r >> 2) + 4 * hi;
      pv = (crow <= q5) ? pv : 0.f;
    }
    p[r] = pv;
  }
  l += (((p[0] + p[1]) + (p[2] + p[3])) + ((p[4] + p[5]) + (p[6] + p[7]))) +
       (((p[8] + p[9]) + (p[10] + p[11])) + ((p[12] + p[13]) + (p[14] + p[15])));

  u32 a0 = cvt_pk_bf16(p[0], p[1]), a1 = cvt_pk_bf16(p[2], p[3]);
  u32 b0 = cvt_pk_bf16(p[4], p[5]), b1 = cvt_pk_bf16(p[6], p[7]);
  pswap(a0, b0); pswap(a1, b1);
  u32 c0 = cvt_pk_bf16(p[8], p[9]), c1 = cvt_pk_bf16(p[10], p[11]);
  u32 d0 = cvt_pk_bf16(p[12], p[13]), d1 = cvt_pk_bf16(p[14], p[15]);
  pswap(c0, d0); pswap(c1, d1);
  u32x4 t0; t0[0] = a0; t0[1] = a1; t0[2] = b0; t0[3] = b1;
  u32x4 t1; t1[0] = c0; t1[1] = c1; t1[2] = d0; t1[3] = d1;
  bf16x8 pa0 = __builtin_bit_cast(bf16x8, t0);  // keys +0..15, k-slot order
  bf16x8 pa1 = __builtin_bit_cast(bf16x8, t1);  // keys +16..31

  __builtin_amdgcn_s_setprio(1);
  acc0 = MFMA32(pa0, v00, acc0);
  acc1 = MFMA32(pa0, v01, acc1);
  acc0 = MFMA32(pa1, v10, acc0);
  acc1 = MFMA32(pa1, v11, acc1);
  __builtin_amdgcn_s_setprio(0);
}

// Q,K: [32 bh][2048][64] bf16 (Q pre-scaled by 0.125*log2e); Vt: [32 bh][64][2048] bf16
__global__ __launch_bounds__(256) void k_attn(const u16* __restrict__ Qg, const u16* __restrict__ Kg,
                                              const u16* __restrict__ Vtg, u16* __restrict__ Og) {
  __shared__ __align__(16) u16 sK[4][64 * 64];  // [key][d] swizzled, 8KB per buffer (4-deep)
  __shared__ __align__(16) u16 sV[4][64 * 64];  // [d][key] swizzled
  const int t = threadIdx.x;
  const int lane = t & 63, q5 = lane & 31, hi = lane >> 5, w = t >> 6;
  const int L = blockIdx.x;
  const int bh = L & 31, pr = L >> 5;           // XCD affinity: L%8 == bh%8; pr 0..7
  const int qtA = pr, qtB = 15 - pr;
  const int b = bh >> 4, h = bh & 15;
  const u16* Qh = Qg + (long)bh * 131072;
  const u16* Kh = Kg + (long)bh * 131072;
  const u16* Vh = Vtg + (long)bh * 131072;
  char* sKb = (char*)sK;
  char* sVb = (char*)sV;

  const int sL_ = qtA * 4 + w, sH_ = qtB * 4 + w;
  const int q0L = sL_ * 32, q0H = sH_ * 32;
  const int nkt = 2 * qtB + 2;  // union k-range (>= 18, so 3-tile prologue is safe)

  // Q fragments for both strips
  const u16* QpL = Qh + (long)(q0L + q5) * 64 + hi * 8;
  bf16x8 qfL0 = *(const bf16x8*)(QpL);
  bf16x8 qfL1 = *(const bf16x8*)(QpL + 16);
  bf16x8 qfL2 = *(const bf16x8*)(QpL + 32);
  bf16x8 qfL3 = *(const bf16x8*)(QpL + 48);
  const u16* QpH = Qh + (long)(q0H + q5) * 64 + hi * 8;
  bf16x8 qfH0 = *(const bf16x8*)(QpH);
  bf16x8 qfH1 = *(const bf16x8*)(QpH + 16);
  bf16x8 qfH2 = *(const bf16x8*)(QpH + 32);
  bf16x8 qfH3 = *(const bf16x8*)(QpH + 48);

  f32x16 aL0, aL1, aH0, aH1;
#pragma unroll
  for (int r = 0; r < 16; ++r) { aL0[r] = 0.f; aL1[r] = 0.f; aH0[r] = 0.f; aH1[r] = 0.f; }
  float lL = 0.f, lH = 0.f;

  auto stage = [&](int buf, int kt) {
    const int kbase = kt << 6;
#pragma unroll
    for (int ps = 0; ps < 2; ++ps) {
      int i = ps * 256 + t;
      int r = i >> 3, c = i & 7, cs = c ^ (r & 7);
      async_lds16(sKb + buf * 8192 + i * 16, Kh + (long)(kbase + r) * 64 + cs * 8);
    }
#pragma unroll
    for (int ps = 0; ps < 2; ++ps) {
      int i = ps * 256 + t;
      int d = i >> 3, c = i & 7, cs = c ^ (d & 7);
      async_lds16(sVb + buf * 8192 + i * 16, Vh + (long)d * 2048 + kbase + cs * 8);
    }
  };

  stage(0, 0);
  stage(1, 1);
  stage(2, 2);
#pragma unroll 1
  for (int kt = 0; kt < nkt; ++kt) {
    const int rem = nkt - kt;
    if (rem >= 3)      asm volatile("s_waitcnt vmcnt(8)" ::: "memory");
    else if (rem == 2) asm volatile("s_waitcnt vmcnt(4)" ::: "memory");
    else               asm volatile("s_waitcnt vmcnt(0)" ::: "memory");
    __builtin_amdgcn_s_barrier();   // all waves done computing tile kt-1; buf (kt-1)&3 free
    __builtin_amdgcn_sched_barrier(0);
    if (kt + 3 < nkt) stage((kt + 3) & 3, kt + 3);  // overwrites freed buffer
    const char* Kt = sKb + (kt & 3) * 8192;
    const char* Vt = sVb + (kt & 3) * 8192;
    const int c2 = 2 * kt;
    // heavy strip
    if (c2 <= sH_) {
      if (c2 == sH_) attn_sub<true>(Kt, Vt, 0, qfH0, qfH1, qfH2, qfH3, aH0, aH1, lH, q5, hi);
      else           attn_sub<false>(Kt, Vt, 0, qfH0, qfH1, qfH2, qfH3, aH0, aH1, lH, q5, hi);
    }
    if (c2 + 1 <= sH_) {
      if (c2 + 1 == sH_) attn_sub<true>(Kt, Vt, 1, qfH0, qfH1, qfH2, qfH3, aH0, aH1, lH, q5, hi);
      else               attn_sub<false>(Kt, Vt, 1, qfH0, qfH1, qfH2, qfH3, aH0, aH1, lH, q5, hi);
    }
    // light strip
    if (c2 <= sL_) {
      if (c2 == sL_) attn_sub<true>(Kt, Vt, 0, qfL0, qfL1, qfL2, qfL3, aL0, aL1, lL, q5, hi);
      else           attn_sub<false>(Kt, Vt, 0, qfL0, qfL1, qfL2, qfL3, aL0, aL1, lL, q5, hi);
    }
    if (c2 + 1 <= sL_) {
      if (c2 + 1 == sL_) attn_sub<true>(Kt, Vt, 1, qfL0, qfL1, qfL2, qfL3, aL0, aL1, lL, q5, hi);
      else               attn_sub<false>(Kt, Vt, 1, qfL0, qfL1, qfL2, qfL3, aL0, aL1, lL, q5, hi);
    }
  }

  // epilogues (no LDS use)
  const long orow_base = (long)b * 2048;
  lH += __shfl_xor(lH, 32);
  float liH = 1.0f / lH;
#pragma unroll
  for (int r = 0; r < 16; ++r) {
    int crow = (r & 3) + 8 * (r >> 2) + 4 * hi;
    float lf = __shfl(liH, crow);
    long orow = orow_base + q0H + crow;
    Og[orow * 1024 + h * 64 + q5] = f2bf(aH0[r] * lf);
    Og[orow * 1024 + h * 64 + 32 + q5] = f2bf(aH1[r] * lf);
  }
  lL += __shfl_xor(lL, 32);
  float liL = 1.0f / lL;
#pragma unroll
  for (int r = 0; r < 16; ++r) {
    int crow = (r & 3) + 8 * (r >> 2) + 4 * hi;
    float lf = __shfl(liL, crow);
    long orow = orow_base + q0L + crow;
    Og[orow * 1024 + h * 64 + q5] = f2bf(aL0[r] * lf);
    Og[orow * 1024 + h * 64 + 32 + q5] = f2bf(aL1[r] * lf);
  }
}

// ---------------- launch ----------------

extern "C" void kernel_launch(void* const* d_in, const int* in_sizes, int n_in,
                              void* d_out, int out_size, void* d_ws, size_t ws_size,
                              hipStream_t stream) {
  const float* x = (const float*)d_in[0];
  const float* w_qkv = (const float*)d_in[1];
  const float* w_out = (const float*)d_in[2];
  float* out = (float*)d_out;
  char* ws = (char*)d_ws;

  u16* xb    = (u16*)(ws + 0);          // 8 MB, reused as Ob after attention
  u16* wqkvT = (u16*)(ws + 8388608L);   // 6 MB
  u16* woutT = (u16*)(ws + 14680064L);  // 2 MB
  u16* Qb    = (u16*)(ws + 16777216L);  // 8 MB
  u16* Kb    = (u16*)(ws + 25165824L);  // 8 MB
  u16* Vt    = (u16*)(ws + 33554432L);  // 8 MB (written transposed by GEMM1)
  u16* Ob    = xb;                      // alias: xb dead after GEMM1

  k_prep<<<dim3(8192), 256, 0, stream>>>(x, xb, w_qkv, wqkvT, w_out, woutT);
  k_gemm_qkv<<<dim3(256), 512, 0, stream>>>(xb, wqkvT, Qb, Kb, Vt);
  k_attn<<<dim3(256), 256, 0, stream>>>(Qb, Kb, Vt, Ob);
  k_gemm_out<<<dim3(256), 256, 0, stream>>>(Ob, woutT, out);
}

// Round 23
// 107.260 us; speedup vs baseline: 1.0571x; 1.0571x over previous
//
#include <hip/hip_runtime.h>

typedef unsigned short u16;
typedef unsigned int u32;
typedef __attribute__((ext_vector_type(8))) short bf16x8;
typedef __attribute__((ext_vector_type(4))) float f32x4;
typedef __attribute__((ext_vector_type(16))) float f32x16;
typedef __attribute__((ext_vector_type(4))) u32 u32x4;

#define MFMA16(a, b, c) __builtin_amdgcn_mfma_f32_16x16x32_bf16((a), (b), (c), 0, 0, 0)
#define MFMA32(a, b, c) __builtin_amdgcn_mfma_f32_32x32x16_bf16((a), (b), (c), 0, 0, 0)

__device__ __forceinline__ void async_lds16(void* lds, const void* g) {
  __builtin_amdgcn_global_load_lds(
      (const __attribute__((address_space(1))) void*)g,
      (__attribute__((address_space(3))) void*)lds, 16, 0, 0);
}

__device__ __forceinline__ u16 f2bf(float f) {
  union { float f; unsigned u; } v; v.f = f;
  unsigned r = v.u + 0x7fffu + ((v.u >> 16) & 1u);
  return (u16)(r >> 16);
}

__device__ __forceinline__ u32 cvt_pk_bf16(float lo, float hi) {
  u32 r;
  asm("v_cvt_pk_bf16_f32 %0, %1, %2" : "=v"(r) : "v"(lo), "v"(hi));
  return r;
}

__device__ __forceinline__ float exp2_fast(float x) {
  float r;
  asm("v_exp_f32 %0, %1" : "=v"(r) : "v"(x));
  return r;
}

// swaps a's hi-32 lanes with b's lo-32 lanes
__device__ __forceinline__ void pswap(u32& a, u32& b) {
  asm("v_permlane32_swap_b32 %0, %1" : "+v"(a), "+v"(b));
}

// ---------------- fused preprocess kernel ----------------
// blocks [0,4096): f32->bf16 cvt of x; [4096,7168): w_qkv transpose (96x32);
// [7168,8192): w_out transpose (32x32).

__device__ __forceinline__ void transpose_cvt_body(const float* __restrict__ in, u16* __restrict__ out,
                                                   int R, int C, int bx, int by,
                                                   float (*tile)[33]) {
  int c0 = bx * 32, r0 = by * 32;
  int tx = threadIdx.x & 31, ty = threadIdx.x >> 5;
#pragma unroll
  for (int i = 0; i < 32; i += 8)
    tile[ty + i][tx] = in[(long)(r0 + ty + i) * C + c0 + tx];
  __syncthreads();
#pragma unroll
  for (int i = 0; i < 32; i += 8)
    out[(long)(c0 + ty + i) * R + r0 + tx] = f2bf(tile[tx][ty + i]);
}

__global__ __launch_bounds__(256) void k_prep(const float* __restrict__ x, u16* __restrict__ xb,
                                              const float* __restrict__ w_qkv, u16* __restrict__ wqkvT,
                                              const float* __restrict__ w_out, u16* __restrict__ woutT) {
  __shared__ float tile[32][33];
  const int B = blockIdx.x;
  if (B < 4096) {
    int i = (B * 256 + threadIdx.x) * 4;
    float4 v = *(const float4*)(x + i);
    ushort4 o;
    o.x = f2bf(v.x); o.y = f2bf(v.y); o.z = f2bf(v.z); o.w = f2bf(v.w);
    *(ushort4*)(xb + i) = o;
  } else if (B < 7168) {
    int bb = B - 4096;
    transpose_cvt_body(w_qkv, wqkvT, 1024, 3072, bb % 96, bb / 96, tile);
  } else {
    int bb = B - 7168;
    transpose_cvt_body(w_out, woutT, 1024, 1024, bb & 31, bb >> 5, tile);
  }
}

// ---------------- NT GEMM core (counted-vmcnt single-barrier pipeline) ----------------

template <int BM, int BN, int NW, int WN, int WCS, int MR, int NR, int NLD>
__device__ __forceinline__ void gemm_core_pipe(const u16* __restrict__ A, const u16* __restrict__ Bt,
                                               int K, long row0, long col0,
                                               u16* sA, u16* sB, f32x4 (&acc)[MR][NR]) {
  const int NTHR = NW * 64;
  const int ABYTES = BM * 64 * 2;
  const int BBYTES = BN * 64 * 2;
  const int t = threadIdx.x;
  const int lane = t & 63, g = lane >> 4, m16 = lane & 15;
  const int wid = t >> 6, wr = wid / WN, wc = wid % WN;
  const int nkt = K >> 6;

  auto stage = [&](int buf, int kt) {
    const int k0 = kt << 6;
#pragma unroll
    for (int it = 0; it < ABYTES / (NTHR * 16); ++it) {
      int i = it * NTHR + t;
      int r = i >> 3, c = i & 7, cs = c ^ (r & 7);
      async_lds16((char*)sA + buf * ABYTES + i * 16, A + (row0 + r) * K + k0 + cs * 8);
    }
#pragma unroll
    for (int it = 0; it < BBYTES / (NTHR * 16); ++it) {
      int i = it * NTHR + t;
      int r = i >> 3, c = i & 7, cs = c ^ (r & 7);
      async_lds16((char*)sB + buf * BBYTES + i * 16, Bt + (col0 + r) * K + k0 + cs * 8);
    }
  };

  stage(0, 0);
  stage(1, 1);
  int cur = 0;
  for (int kt = 0; kt < nkt; ++kt) {
    if (kt + 1 < nkt) {
      if constexpr (NLD == 7) asm volatile("s_waitcnt vmcnt(7)" ::: "memory");
      else                    asm volatile("s_waitcnt vmcnt(8)" ::: "memory");
    } else {
      asm volatile("s_waitcnt vmcnt(0)" ::: "memory");
    }
    __builtin_amdgcn_s_barrier();
    __builtin_amdgcn_sched_barrier(0);
    const char* bA = (const char*)sA + cur * ABYTES;
    const char* bB = (const char*)sB + cur * BBYTES;
#pragma unroll
    for (int kk6 = 0; kk6 < 2; ++kk6) {
      const int ke = kk6 * 32 + 8 * g;
      bf16x8 av[MR], bv[NR];
#pragma unroll
      for (int mi = 0; mi < MR; ++mi) {
        int row = wr * (MR * 16) + mi * 16 + m16;
        av[mi] = *(const bf16x8*)(bA + (row << 7) + ((ke << 1) ^ ((row & 7) << 4)));
      }
#pragma unroll
      for (int ni = 0; ni < NR; ++ni) {
        int row = wc * WCS + ni * 16 + m16;
        bv[ni] = *(const bf16x8*)(bB + (row << 7) + ((ke << 1) ^ ((row & 7) << 4)));
      }
#pragma unroll
      for (int mi = 0; mi < MR; ++mi)
#pragma unroll
        for (int ni = 0; ni < NR; ++ni)
          acc[mi][ni] = MFMA16(av[mi], bv[ni], acc[mi][ni]);
    }
    __builtin_amdgcn_sched_barrier(0);
    __builtin_amdgcn_s_barrier();
    if (kt + 2 < nkt) stage(cur, kt + 2);
    cur ^= 1;
  }
}

// GEMM1: xb[4096][1024] x wqkvT[3072][1024]^T, 256x192 tile, 512 thr (8 waves 2x4).
// Grid 256 = 1 block/CU; col0 = colt*192 -> block maps to head colt.
// V is written DIRECTLY in transposed layout Vt[bh][d][s].
__global__ __launch_bounds__(512, 2) void k_gemm_qkv(const u16* __restrict__ xb, const u16* __restrict__ wT,
                                                     u16* __restrict__ Qo, u16* __restrict__ Ko,
                                                     u16* __restrict__ Vt) {
  __shared__ __align__(16) u16 sA[2 * 256 * 64];  // 64KB
  __shared__ __align__(16) u16 sB[2 * 192 * 64];  // 48KB
  f32x4 acc[8][3];
  const f32x4 z = {0.f, 0.f, 0.f, 0.f};
#pragma unroll
  for (int mi = 0; mi < 8; ++mi)
#pragma unroll
    for (int ni = 0; ni < 3; ++ni) acc[mi][ni] = z;
  const int L = blockIdx.x;
  const int xcd = L & 7, idx = L >> 3;          // idx 0..31
  const int rowt = xcd * 2 + (idx & 1);         // 0..15
  const int colt = idx >> 1;                    // 0..15 (= head h)
  long row0 = (long)rowt * 256, col0 = (long)colt * 192;
  gemm_core_pipe<256, 192, 8, 4, 48, 8, 3, 7>(xb, wT, 1024, row0, col0, sA, sB, acc);
  const int t = threadIdx.x;
  const int lane = t & 63, g = lane >> 4, m16 = lane & 15;
  const int wid = t >> 6, wr = wid >> 2, wc = wid & 3;
  const int h = colt;
#pragma unroll
  for (int mi = 0; mi < 8; ++mi) {
#pragma unroll
    for (int ni = 0; ni < 3; ++ni) {
      int rem = wc * 48 + ni * 16 + m16;        // 0..191 within head
      int which = rem >> 6, d = rem & 63;
      int row_base = (int)row0 + wr * 128 + mi * 16 + 4 * g;  // multiple of 4
      int b = row_base >> 11, s = row_base & 2047;
      if (which == 2) {
        // Vt[bh][d][s..s+3]: contiguous, 8B-aligned
        ushort4 o;
        o.x = f2bf(acc[mi][ni][0]); o.y = f2bf(acc[mi][ni][1]);
        o.z = f2bf(acc[mi][ni][2]); o.w = f2bf(acc[mi][ni][3]);
        *(ushort4*)(Vt + ((long)(b * 16 + h)) * 131072 + (long)d * 2048 + s) = o;
      } else {
        long off = (((long)(b * 16 + h)) * 2048 + s) * 64 + d;
#pragma unroll
        for (int r = 0; r < 4; ++r) {
          float v = acc[mi][ni][r];
          if (which == 0) Qo[off + (long)r * 64] = f2bf(v * 0.18033688f);  // 0.125*log2e
          else            Ko[off + (long)r * 64] = f2bf(v);
        }
      }
    }
  }
}

// GEMM2: Ob[4096][1024] x woutT[1024][1024]^T -> out f32 [4096][1024]
__global__ __launch_bounds__(256) void k_gemm_out(const u16* __restrict__ Ob, const u16* __restrict__ wT,
                                                  float* __restrict__ out) {
  __shared__ __align__(16) u16 sA[2 * 128 * 64];  // 32KB
  __shared__ __align__(16) u16 sB[2 * 128 * 64];  // 32KB
  f32x4 acc[4][4];
  const f32x4 z = {0.f, 0.f, 0.f, 0.f};
#pragma unroll
  for (int mi = 0; mi < 4; ++mi)
#pragma unroll
    for (int ni = 0; ni < 4; ++ni) acc[mi][ni] = z;
  const int L = blockIdx.x;
  const int xcd = L & 7, idx = L >> 3;          // idx 0..31
  const int rowt = xcd * 4 + (idx & 3);         // 0..31
  const int colt = idx >> 2;                    // 0..7
  long row0 = (long)rowt * 128, col0 = (long)colt * 128;
  gemm_core_pipe<128, 128, 4, 2, 64, 4, 4, 8>(Ob, wT, 1024, row0, col0, sA, sB, acc);
  const int t = threadIdx.x;
  const int lane = t & 63, g = lane >> 4, m16 = lane & 15;
  const int wid = t >> 6, wr = wid >> 1, wc = wid & 1;
#pragma unroll
  for (int mi = 0; mi < 4; ++mi) {
#pragma unroll
    for (int ni = 0; ni < 4; ++ni) {
#pragma unroll
      for (int r = 0; r < 4; ++r) {
        long row = row0 + wr * 64 + mi * 16 + 4 * g + r;
        long col = col0 + wc * 64 + ni * 16 + m16;
        out[row * 1024 + col] = acc[mi][ni][r];
      }
    }
  }
}

// ---------------- causal flash attention: r19/r21 green structure (4-deep LDS pipeline) ----------------
// Block (bh, pr) = 256 thr = 4 waves; wave w owns heavy strip qtB*4+w and light
// strip qtA*4+w (uniform ~64-66 subs/wave). 4 K/V buffers (64KB); steady-state
// wait vmcnt(12) (4 loads/thread/tile x 3 tiles in flight), exact 4-case tail.
// Two barriers per tile (phase-locked waves) — measured best (r21: 46.7us).

template <bool DIAG>
__device__ __forceinline__ void attn_sub(const char* Kt, const char* Vt, int bsub,
                                         bf16x8 qf0, bf16x8 qf1, bf16x8 qf2, bf16x8 qf3,
                                         f32x16& acc0, f32x16& acc1, float& l,
                                         int q5, int hi) {
  const int x7 = q5 & 7;
  const int rowK = (bsub * 32 + q5) << 7;
  bf16x8 k0 = *(const bf16x8*)(Kt + rowK + (((0 + hi) ^ x7) << 4));
  bf16x8 k1 = *(const bf16x8*)(Kt + rowK + (((2 + hi) ^ x7) << 4));
  bf16x8 k2 = *(const bf16x8*)(Kt + rowK + (((4 + hi) ^ x7) << 4));
  bf16x8 k3 = *(const bf16x8*)(Kt + rowK + (((6 + hi) ^ x7) << 4));
  const int rowV0 = q5 << 7, rowV1 = (q5 + 32) << 7;
  bf16x8 v00 = *(const bf16x8*)(Vt + rowV0 + (((bsub * 4 + 0 + hi) ^ x7) << 4));
  bf16x8 v01 = *(const bf16x8*)(Vt + rowV1 + (((bsub * 4 + 0 + hi) ^ x7) << 4));
  bf16x8 v10 = *(const bf16x8*)(Vt + rowV0 + (((bsub * 4 + 2 + hi) ^ x7) << 4));
  bf16x8 v11 = *(const bf16x8*)(Vt + rowV1 + (((bsub * 4 + 2 + hi) ^ x7) << 4));

  f32x16 s;
#pragma unroll
  for (int r = 0; r < 16; ++r) s[r] = 0.f;
  __builtin_amdgcn_s_setprio(1);
  s = MFMA32(k0, qf0, s);
  s = MFMA32(k1, qf1, s);
  s = MFMA32(k2, qf2, s);
  s = MFMA32(k3, qf3, s);
  __builtin_amdgcn_s_setprio(0);

  float p[16];
#pragma unroll
  for (int r = 0; r < 16; ++r) {
    float pv = exp2_fast(s[r]);
    if (DIAG) {
      int crow = (r & 3) + 8 * (r >> 2) + 4 * hi;
      pv = (crow <= q5) ? pv : 0.f;
    }
    p[r] = pv;
  }
  l += (((p[0] + p[1]) + (p[2] + p[3])) + ((p[4] + p[5]) + (p[6] + p[7]))) +
       (((p[8] + p[9]) + (p[10] + p[11])) + ((p[12] + p[13]) + (p[14] + p[15])));

  u32 a0 = cvt_pk_bf16(p[0], p[1]), a1 = cvt_pk_bf16(p[2], p[3]);
  u32 b0 = cvt_pk_bf16(p[4], p[5]), b1 = cvt_pk_bf16(p[6], p[7]);
  pswap(a0, b0); pswap(a1, b1);
  u32 c0 = cvt_pk_bf16(p[8], p[9]), c1 = cvt_pk_bf16(p[10], p[11]);
  u32 d0 = cvt_pk_bf16(p[12], p[13]), d1 = cvt_pk_bf16(p[14], p[15]);
  pswap(c0, d0); pswap(c1, d1);
  u32x4 t0; t0[0] = a0; t0[1] = a1; t0[2] = b0; t0[3] = b1;
  u32x4 t1; t1[0] = c0; t1[1] = c1; t1[2] = d0; t1[3] = d1;
  bf16x8 pa0 = __builtin_bit_cast(bf16x8, t0);  // keys +0..15, k-slot order
  bf16x8 pa1 = __builtin_bit_cast(bf16x8, t1);  // keys +16..31

  __builtin_amdgcn_s_setprio(1);
  acc0 = MFMA32(pa0, v00, acc0);
  acc1 = MFMA32(pa0, v01, acc1);
  acc0 = MFMA32(pa1, v10, acc0);
  acc1 = MFMA32(pa1, v11, acc1);
  __builtin_amdgcn_s_setprio(0);
}

// Q,K: [32 bh][2048][64] bf16 (Q pre-scaled by 0.125*log2e); Vt: [32 bh][64][2048] bf16
__global__ __launch_bounds__(256) void k_attn(const u16* __restrict__ Qg, const u16* __restrict__ Kg,
                                              const u16* __restrict__ Vtg, u16* __restrict__ Og) {
  __shared__ __align__(16) u16 sK[4][64 * 64];  // [key][d] swizzled, 8KB per buffer (4-deep)
  __shared__ __align__(16) u16 sV[4][64 * 64];  // [d][key] swizzled
  const int t = threadIdx.x;
  const int lane = t & 63, q5 = lane & 31, hi = lane >> 5, w = t >> 6;
  const int L = blockIdx.x;
  const int bh = L & 31, pr = L >> 5;           // XCD affinity: L%8 == bh%8; pr 0..7
  const int qtA = pr, qtB = 15 - pr;
  const int b = bh >> 4, h = bh & 15;
  const u16* Qh = Qg + (long)bh * 131072;
  const u16* Kh = Kg + (long)bh * 131072;
  const u16* Vh = Vtg + (long)bh * 131072;
  char* sKb = (char*)sK;
  char* sVb = (char*)sV;

  const int sL_ = qtA * 4 + w, sH_ = qtB * 4 + w;
  const int q0L = sL_ * 32, q0H = sH_ * 32;
  const int nkt = 2 * qtB + 2;  // union k-range (>= 18, so 4-tile prologue is safe)

  // Q fragments for both strips
  const u16* QpL = Qh + (long)(q0L + q5) * 64 + hi * 8;
  bf16x8 qfL0 = *(const bf16x8*)(QpL);
  bf16x8 qfL1 = *(const bf16x8*)(QpL + 16);
  bf16x8 qfL2 = *(const bf16x8*)(QpL + 32);
  bf16x8 qfL3 = *(const bf16x8*)(QpL + 48);
  const u16* QpH = Qh + (long)(q0H + q5) * 64 + hi * 8;
  bf16x8 qfH0 = *(const bf16x8*)(QpH);
  bf16x8 qfH1 = *(const bf16x8*)(QpH + 16);
  bf16x8 qfH2 = *(const bf16x8*)(QpH + 32);
  bf16x8 qfH3 = *(const bf16x8*)(QpH + 48);

  f32x16 aL0, aL1, aH0, aH1;
#pragma unroll
  for (int r = 0; r < 16; ++r) { aL0[r] = 0.f; aL1[r] = 0.f; aH0[r] = 0.f; aH1[r] = 0.f; }
  float lL = 0.f, lH = 0.f;

  auto stage = [&](int buf, int kt) {
    const int kbase = kt << 6;
#pragma unroll
    for (int ps = 0; ps < 2; ++ps) {
      int i = ps * 256 + t;
      int r = i >> 3, c = i & 7, cs = c ^ (r & 7);
      async_lds16(sKb + buf * 8192 + i * 16, Kh + (long)(kbase + r) * 64 + cs * 8);
    }
#pragma unroll
    for (int ps = 0; ps < 2; ++ps) {
      int i = ps * 256 + t;
      int d = i >> 3, c = i & 7, cs = c ^ (d & 7);
      async_lds16(sVb + buf * 8192 + i * 16, Vh + (long)d * 2048 + kbase + cs * 8);
    }
  };

  stage(0, 0);
  stage(1, 1);
  stage(2, 2);
  stage(3, 3);
#pragma unroll 1
  for (int kt = 0; kt < nkt; ++kt) {
    const int rem = nkt - kt;
    if (rem > 3)       asm volatile("s_waitcnt vmcnt(12)" ::: "memory");
    else if (rem == 3) asm volatile("s_waitcnt vmcnt(8)" ::: "memory");
    else if (rem == 2) asm volatile("s_waitcnt vmcnt(4)" ::: "memory");
    else               asm volatile("s_waitcnt vmcnt(0)" ::: "memory");
    __builtin_amdgcn_s_barrier();
    __builtin_amdgcn_sched_barrier(0);
    const char* Kt = sKb + (kt & 3) * 8192;
    const char* Vt = sVb + (kt & 3) * 8192;
    const int c2 = 2 * kt;
    // heavy strip
    if (c2 <= sH_) {
      if (c2 == sH_) attn_sub<true>(Kt, Vt, 0, qfH0, qfH1, qfH2, qfH3, aH0, aH1, lH, q5, hi);
      else           attn_sub<false>(Kt, Vt, 0, qfH0, qfH1, qfH2, qfH3, aH0, aH1, lH, q5, hi);
    }
    if (c2 + 1 <= sH_) {
      if (c2 + 1 == sH_) attn_sub<true>(Kt, Vt, 1, qfH0, qfH1, qfH2, qfH3, aH0, aH1, lH, q5, hi);
      else               attn_sub<false>(Kt, Vt, 1, qfH0, qfH1, qfH2, qfH3, aH0, aH1, lH, q5, hi);
    }
    // light strip
    if (c2 <= sL_) {
      if (c2 == sL_) attn_sub<true>(Kt, Vt, 0, qfL0, qfL1, qfL2, qfL3, aL0, aL1, lL, q5, hi);
      else           attn_sub<false>(Kt, Vt, 0, qfL0, qfL1, qfL2, qfL3, aL0, aL1, lL, q5, hi);
    }
    if (c2 + 1 <= sL_) {
      if (c2 + 1 == sL_) attn_sub<true>(Kt, Vt, 1, qfL0, qfL1, qfL2, qfL3, aL0, aL1, lL, q5, hi);
      else               attn_sub<false>(Kt, Vt, 1, qfL0, qfL1, qfL2, qfL3, aL0, aL1, lL, q5, hi);
    }
    __builtin_amdgcn_sched_barrier(0);
    __builtin_amdgcn_s_barrier();
    if (kt + 4 < nkt) stage(kt & 3, kt + 4);
  }

  // epilogues (no LDS use)
  const long orow_base = (long)b * 2048;
  lH += __shfl_xor(lH, 32);
  float liH = 1.0f / lH;
#pragma unroll
  for (int r = 0; r < 16; ++r) {
    int crow = (r & 3) + 8 * (r >> 2) + 4 * hi;
    float lf = __shfl(liH, crow);
    long orow = orow_base + q0H + crow;
    Og[orow * 1024 + h * 64 + q5] = f2bf(aH0[r] * lf);
    Og[orow * 1024 + h * 64 + 32 + q5] = f2bf(aH1[r] * lf);
  }
  lL += __shfl_xor(lL, 32);
  float liL = 1.0f / lL;
#pragma unroll
  for (int r = 0; r < 16; ++r) {
    int crow = (r & 3) + 8 * (r >> 2) + 4 * hi;
    float lf = __shfl(liL, crow);
    long orow = orow_base + q0L + crow;
    Og[orow * 1024 + h * 64 + q5] = f2bf(aL0[r] * lf);
    Og[orow * 1024 + h * 64 + 32 + q5] = f2bf(aL1[r] * lf);
  }
}

// ---------------- launch ----------------

extern "C" void kernel_launch(void* const* d_in, const int* in_sizes, int n_in,
                              void* d_out, int out_size, void* d_ws, size_t ws_size,
                              hipStream_t stream) {
  const float* x = (const float*)d_in[0];
  const float* w_qkv = (const float*)d_in[1];
  const float* w_out = (const float*)d_in[2];
  float* out = (float*)d_out;
  char* ws = (char*)d_ws;

  u16* xb    = (u16*)(ws + 0);          // 8 MB, reused as Ob after attention
  u16* wqkvT = (u16*)(ws + 8388608L);   // 6 MB
  u16* woutT = (u16*)(ws + 14680064L);  // 2 MB
  u16* Qb    = (u16*)(ws + 16777216L);  // 8 MB
  u16* Kb    = (u16*)(ws + 25165824L);  // 8 MB
  u16* Vt    = (u16*)(ws + 33554432L);  // 8 MB (written transposed by GEMM1)
  u16* Ob    = xb;                      // alias: xb dead after GEMM1

  k_prep<<<dim3(8192), 256, 0, stream>>>(x, xb, w_qkv, wqkvT, w_out, woutT);
  k_gemm_qkv<<<dim3(256), 512, 0, stream>>>(xb, wqkvT, Qb, Kb, Vt);
  k_attn<<<dim3(256), 256, 0, stream>>>(Qb, Kb, Vt, Ob);
  k_gemm_out<<<dim3(256), 256, 0, stream>>>(Ob, woutT, out);
}

// Round 24
// 102.987 us; speedup vs baseline: 1.1009x; 1.0415x over previous
//
#include <hip/hip_runtime.h>

typedef unsigned short u16;
typedef unsigned int u32;
typedef __attribute__((ext_vector_type(8))) short bf16x8;
typedef __attribute__((ext_vector_type(4))) float f32x4;
typedef __attribute__((ext_vector_type(16))) float f32x16;
typedef __attribute__((ext_vector_type(4))) u32 u32x4;

#define MFMA16(a, b, c) __builtin_amdgcn_mfma_f32_16x16x32_bf16((a), (b), (c), 0, 0, 0)
#define MFMA32(a, b, c) __builtin_amdgcn_mfma_f32_32x32x16_bf16((a), (b), (c), 0, 0, 0)

__device__ __forceinline__ void async_lds16(void* lds, const void* g) {
  __builtin_amdgcn_global_load_lds(
      (const __attribute__((address_space(1))) void*)g,
      (__attribute__((address_space(3))) void*)lds, 16, 0, 0);
}

__device__ __forceinline__ u16 f2bf(float f) {
  union { float f; unsigned u; } v; v.f = f;
  unsigned r = v.u + 0x7fffu + ((v.u >> 16) & 1u);
  return (u16)(r >> 16);
}

__device__ __forceinline__ u32 cvt_pk_bf16(float lo, float hi) {
  u32 r;
  asm("v_cvt_pk_bf16_f32 %0, %1, %2" : "=v"(r) : "v"(lo), "v"(hi));
  return r;
}

__device__ __forceinline__ float exp2_fast(float x) {
  float r;
  asm("v_exp_f32 %0, %1" : "=v"(r) : "v"(x));
  return r;
}

// swaps a's hi-32 lanes with b's lo-32 lanes
__device__ __forceinline__ void pswap(u32& a, u32& b) {
  asm("v_permlane32_swap_b32 %0, %1" : "+v"(a), "+v"(b));
}

// ---------------- fused preprocess kernel ----------------
// blocks [0,4096): f32->bf16 cvt of x; [4096,7168): w_qkv transpose (96x32);
// [7168,8192): w_out transpose (32x32).

__device__ __forceinline__ void transpose_cvt_body(const float* __restrict__ in, u16* __restrict__ out,
                                                   int R, int C, int bx, int by,
                                                   float (*tile)[33]) {
  int c0 = bx * 32, r0 = by * 32;
  int tx = threadIdx.x & 31, ty = threadIdx.x >> 5;
#pragma unroll
  for (int i = 0; i < 32; i += 8)
    tile[ty + i][tx] = in[(long)(r0 + ty + i) * C + c0 + tx];
  __syncthreads();
#pragma unroll
  for (int i = 0; i < 32; i += 8)
    out[(long)(c0 + ty + i) * R + r0 + tx] = f2bf(tile[tx][ty + i]);
}

__global__ __launch_bounds__(256) void k_prep(const float* __restrict__ x, u16* __restrict__ xb,
                                              const float* __restrict__ w_qkv, u16* __restrict__ wqkvT,
                                              const float* __restrict__ w_out, u16* __restrict__ woutT) {
  __shared__ float tile[32][33];
  const int B = blockIdx.x;
  if (B < 4096) {
    int i = (B * 256 + threadIdx.x) * 4;
    float4 v = *(const float4*)(x + i);
    ushort4 o;
    o.x = f2bf(v.x); o.y = f2bf(v.y); o.z = f2bf(v.z); o.w = f2bf(v.w);
    *(ushort4*)(xb + i) = o;
  } else if (B < 7168) {
    int bb = B - 4096;
    transpose_cvt_body(w_qkv, wqkvT, 1024, 3072, bb % 96, bb / 96, tile);
  } else {
    int bb = B - 7168;
    transpose_cvt_body(w_out, woutT, 1024, 1024, bb & 31, bb >> 5, tile);
  }
}

// ---------------- NT GEMM core (counted-vmcnt single-barrier pipeline) ----------------

template <int BM, int BN, int NW, int WN, int WCS, int MR, int NR, int NLD>
__device__ __forceinline__ void gemm_core_pipe(const u16* __restrict__ A, const u16* __restrict__ Bt,
                                               int K, long row0, long col0,
                                               u16* sA, u16* sB, f32x4 (&acc)[MR][NR]) {
  const int NTHR = NW * 64;
  const int ABYTES = BM * 64 * 2;
  const int BBYTES = BN * 64 * 2;
  const int t = threadIdx.x;
  const int lane = t & 63, g = lane >> 4, m16 = lane & 15;
  const int wid = t >> 6, wr = wid / WN, wc = wid % WN;
  const int nkt = K >> 6;

  auto stage = [&](int buf, int kt) {
    const int k0 = kt << 6;
#pragma unroll
    for (int it = 0; it < ABYTES / (NTHR * 16); ++it) {
      int i = it * NTHR + t;
      int r = i >> 3, c = i & 7, cs = c ^ (r & 7);
      async_lds16((char*)sA + buf * ABYTES + i * 16, A + (row0 + r) * K + k0 + cs * 8);
    }
#pragma unroll
    for (int it = 0; it < BBYTES / (NTHR * 16); ++it) {
      int i = it * NTHR + t;
      int r = i >> 3, c = i & 7, cs = c ^ (r & 7);
      async_lds16((char*)sB + buf * BBYTES + i * 16, Bt + (col0 + r) * K + k0 + cs * 8);
    }
  };

  stage(0, 0);
  stage(1, 1);
  int cur = 0;
  for (int kt = 0; kt < nkt; ++kt) {
    if (kt + 1 < nkt) {
      if constexpr (NLD == 7) asm volatile("s_waitcnt vmcnt(7)" ::: "memory");
      else                    asm volatile("s_waitcnt vmcnt(8)" ::: "memory");
    } else {
      asm volatile("s_waitcnt vmcnt(0)" ::: "memory");
    }
    __builtin_amdgcn_s_barrier();
    __builtin_amdgcn_sched_barrier(0);
    const char* bA = (const char*)sA + cur * ABYTES;
    const char* bB = (const char*)sB + cur * BBYTES;
#pragma unroll
    for (int kk6 = 0; kk6 < 2; ++kk6) {
      const int ke = kk6 * 32 + 8 * g;
      bf16x8 av[MR], bv[NR];
#pragma unroll
      for (int mi = 0; mi < MR; ++mi) {
        int row = wr * (MR * 16) + mi * 16 + m16;
        av[mi] = *(const bf16x8*)(bA + (row << 7) + ((ke << 1) ^ ((row & 7) << 4)));
      }
#pragma unroll
      for (int ni = 0; ni < NR; ++ni) {
        int row = wc * WCS + ni * 16 + m16;
        bv[ni] = *(const bf16x8*)(bB + (row << 7) + ((ke << 1) ^ ((row & 7) << 4)));
      }
#pragma unroll
      for (int mi = 0; mi < MR; ++mi)
#pragma unroll
        for (int ni = 0; ni < NR; ++ni)
          acc[mi][ni] = MFMA16(av[mi], bv[ni], acc[mi][ni]);
    }
    __builtin_amdgcn_sched_barrier(0);
    __builtin_amdgcn_s_barrier();
    if (kt + 2 < nkt) stage(cur, kt + 2);
    cur ^= 1;
  }
}

// GEMM1: xb[4096][1024] x wqkvT[3072][1024]^T, 256x192 tile, 512 thr (8 waves 2x4).
// Grid 256 = 1 block/CU; col0 = colt*192 -> block maps to head colt.
// V is written DIRECTLY in transposed layout Vt[bh][d][s].
__global__ __launch_bounds__(512, 2) void k_gemm_qkv(const u16* __restrict__ xb, const u16* __restrict__ wT,
                                                     u16* __restrict__ Qo, u16* __restrict__ Ko,
                                                     u16* __restrict__ Vt) {
  __shared__ __align__(16) u16 sA[2 * 256 * 64];  // 64KB
  __shared__ __align__(16) u16 sB[2 * 192 * 64];  // 48KB
  f32x4 acc[8][3];
  const f32x4 z = {0.f, 0.f, 0.f, 0.f};
#pragma unroll
  for (int mi = 0; mi < 8; ++mi)
#pragma unroll
    for (int ni = 0; ni < 3; ++ni) acc[mi][ni] = z;
  const int L = blockIdx.x;
  const int xcd = L & 7, idx = L >> 3;          // idx 0..31
  const int rowt = xcd * 2 + (idx & 1);         // 0..15
  const int colt = idx >> 1;                    // 0..15 (= head h)
  long row0 = (long)rowt * 256, col0 = (long)colt * 192;
  gemm_core_pipe<256, 192, 8, 4, 48, 8, 3, 7>(xb, wT, 1024, row0, col0, sA, sB, acc);
  const int t = threadIdx.x;
  const int lane = t & 63, g = lane >> 4, m16 = lane & 15;
  const int wid = t >> 6, wr = wid >> 2, wc = wid & 3;
  const int h = colt;
#pragma unroll
  for (int mi = 0; mi < 8; ++mi) {
#pragma unroll
    for (int ni = 0; ni < 3; ++ni) {
      int rem = wc * 48 + ni * 16 + m16;        // 0..191 within head
      int which = rem >> 6, d = rem & 63;
      int row_base = (int)row0 + wr * 128 + mi * 16 + 4 * g;  // multiple of 4
      int b = row_base >> 11, s = row_base & 2047;
      if (which == 2) {
        // Vt[bh][d][s..s+3]: contiguous, 8B-aligned
        ushort4 o;
        o.x = f2bf(acc[mi][ni][0]); o.y = f2bf(acc[mi][ni][1]);
        o.z = f2bf(acc[mi][ni][2]); o.w = f2bf(acc[mi][ni][3]);
        *(ushort4*)(Vt + ((long)(b * 16 + h)) * 131072 + (long)d * 2048 + s) = o;
      } else {
        long off = (((long)(b * 16 + h)) * 2048 + s) * 64 + d;
#pragma unroll
        for (int r = 0; r < 4; ++r) {
          float v = acc[mi][ni][r];
          if (which == 0) Qo[off + (long)r * 64] = f2bf(v * 0.18033688f);  // 0.125*log2e
          else            Ko[off + (long)r * 64] = f2bf(v);
        }
      }
    }
  }
}

// GEMM2: Ob[4096][1024] x woutT[1024][1024]^T -> out f32 [4096][1024]
__global__ __launch_bounds__(256) void k_gemm_out(const u16* __restrict__ Ob, const u16* __restrict__ wT,
                                                  float* __restrict__ out) {
  __shared__ __align__(16) u16 sA[2 * 128 * 64];  // 32KB
  __shared__ __align__(16) u16 sB[2 * 128 * 64];  // 32KB
  f32x4 acc[4][4];
  const f32x4 z = {0.f, 0.f, 0.f, 0.f};
#pragma unroll
  for (int mi = 0; mi < 4; ++mi)
#pragma unroll
    for (int ni = 0; ni < 4; ++ni) acc[mi][ni] = z;
  const int L = blockIdx.x;
  const int xcd = L & 7, idx = L >> 3;          // idx 0..31
  const int rowt = xcd * 4 + (idx & 3);         // 0..31
  const int colt = idx >> 2;                    // 0..7
  long row0 = (long)rowt * 128, col0 = (long)colt * 128;
  gemm_core_pipe<128, 128, 4, 2, 64, 4, 4, 8>(Ob, wT, 1024, row0, col0, sA, sB, acc);
  const int t = threadIdx.x;
  const int lane = t & 63, g = lane >> 4, m16 = lane & 15;
  const int wid = t >> 6, wr = wid >> 1, wc = wid & 1;
#pragma unroll
  for (int mi = 0; mi < 4; ++mi) {
#pragma unroll
    for (int ni = 0; ni < 4; ++ni) {
#pragma unroll
      for (int r = 0; r < 4; ++r) {
        long row = row0 + wr * 64 + mi * 16 + 4 * g + r;
        long col = col0 + wc * 64 + ni * 16 + m16;
        out[row * 1024 + col] = acc[mi][ni][r];
      }
    }
  }
}

// ---------------- causal flash attention: KVBLK=128 tiles (4 subs/tile), 2-deep ----------------
// Block (bh, pr) = 256 thr = 4 waves; wave w owns heavy strip qtB*4+w and light
// strip qtA*4+w. Tile = 128 keys: K tile 16KB [key][d], V tile 16KB [d][key=128]
// (row stride 256B), both XOR-swizzled, double-buffered (64KB total). Loop shape
// identical to the green GEMM pipeline: vmcnt(8)/vmcnt(0), two barriers per tile,
// stage(kt+2) after the second barrier. Halves the per-tile fixed cost count.

template <bool DIAG>
__device__ __forceinline__ void attn_sub(const char* Kt, const char* Vt, int bsub,
                                         bf16x8 qf0, bf16x8 qf1, bf16x8 qf2, bf16x8 qf3,
                                         f32x16& acc0, f32x16& acc1, float& l,
                                         int q5, int hi) {
  const int x7 = q5 & 7;
  const int rowK = (bsub * 32 + q5) << 7;          // K row stride 128B (64 d)
  bf16x8 k0 = *(const bf16x8*)(Kt + rowK + (((0 + hi) ^ x7) << 4));
  bf16x8 k1 = *(const bf16x8*)(Kt + rowK + (((2 + hi) ^ x7) << 4));
  bf16x8 k2 = *(const bf16x8*)(Kt + rowK + (((4 + hi) ^ x7) << 4));
  bf16x8 k3 = *(const bf16x8*)(Kt + rowK + (((6 + hi) ^ x7) << 4));
  const int rowV0 = q5 << 8, rowV1 = (q5 + 32) << 8;  // V row stride 256B (128 keys)
  bf16x8 v00 = *(const bf16x8*)(Vt + rowV0 + (((bsub * 4 + 0 + hi) ^ x7) << 4));
  bf16x8 v01 = *(const bf16x8*)(Vt + rowV1 + (((bsub * 4 + 0 + hi) ^ x7) << 4));
  bf16x8 v10 = *(const bf16x8*)(Vt + rowV0 + (((bsub * 4 + 2 + hi) ^ x7) << 4));
  bf16x8 v11 = *(const bf16x8*)(Vt + rowV1 + (((bsub * 4 + 2 + hi) ^ x7) << 4));

  f32x16 s;
#pragma unroll
  for (int r = 0; r < 16; ++r) s[r] = 0.f;
  __builtin_amdgcn_s_setprio(1);
  s = MFMA32(k0, qf0, s);
  s = MFMA32(k1, qf1, s);
  s = MFMA32(k2, qf2, s);
  s = MFMA32(k3, qf3, s);
  __builtin_amdgcn_s_setprio(0);

  float p[16];
#pragma unroll
  for (int r = 0; r < 16; ++r) {
    float pv = exp2_fast(s[r]);
    if (DIAG) {
      int crow = (r & 3) + 8 * (r >> 2) + 4 * hi;
      pv = (crow <= q5) ? pv : 0.f;
    }
    p[r] = pv;
  }
  l += (((p[0] + p[1]) + (p[2] + p[3])) + ((p[4] + p[5]) + (p[6] + p[7]))) +
       (((p[8] + p[9]) + (p[10] + p[11])) + ((p[12] + p[13]) + (p[14] + p[15])));

  u32 a0 = cvt_pk_bf16(p[0], p[1]), a1 = cvt_pk_bf16(p[2], p[3]);
  u32 b0 = cvt_pk_bf16(p[4], p[5]), b1 = cvt_pk_bf16(p[6], p[7]);
  pswap(a0, b0); pswap(a1, b1);
  u32 c0 = cvt_pk_bf16(p[8], p[9]), c1 = cvt_pk_bf16(p[10], p[11]);
  u32 d0 = cvt_pk_bf16(p[12], p[13]), d1 = cvt_pk_bf16(p[14], p[15]);
  pswap(c0, d0); pswap(c1, d1);
  u32x4 t0; t0[0] = a0; t0[1] = a1; t0[2] = b0; t0[3] = b1;
  u32x4 t1; t1[0] = c0; t1[1] = c1; t1[2] = d0; t1[3] = d1;
  bf16x8 pa0 = __builtin_bit_cast(bf16x8, t0);  // keys +0..15, k-slot order
  bf16x8 pa1 = __builtin_bit_cast(bf16x8, t1);  // keys +16..31

  __builtin_amdgcn_s_setprio(1);
  acc0 = MFMA32(pa0, v00, acc0);
  acc1 = MFMA32(pa0, v01, acc1);
  acc0 = MFMA32(pa1, v10, acc0);
  acc1 = MFMA32(pa1, v11, acc1);
  __builtin_amdgcn_s_setprio(0);
}

// Q,K: [32 bh][2048][64] bf16 (Q pre-scaled by 0.125*log2e); Vt: [32 bh][64][2048] bf16
__global__ __launch_bounds__(256) void k_attn(const u16* __restrict__ Qg, const u16* __restrict__ Kg,
                                              const u16* __restrict__ Vtg, u16* __restrict__ Og) {
  __shared__ __align__(16) u16 sK[2][128 * 64];  // [key][d] swizzled, 16KB per buffer
  __shared__ __align__(16) u16 sV[2][64 * 128];  // [d][key] swizzled, 16KB per buffer
  const int t = threadIdx.x;
  const int lane = t & 63, q5 = lane & 31, hi = lane >> 5, w = t >> 6;
  const int L = blockIdx.x;
  const int bh = L & 31, pr = L >> 5;           // XCD affinity: L%8 == bh%8; pr 0..7
  const int qtA = pr, qtB = 15 - pr;
  const int b = bh >> 4, h = bh & 15;
  const u16* Qh = Qg + (long)bh * 131072;
  const u16* Kh = Kg + (long)bh * 131072;
  const u16* Vh = Vtg + (long)bh * 131072;
  char* sKb = (char*)sK;
  char* sVb = (char*)sV;

  const int sL_ = qtA * 4 + w, sH_ = qtB * 4 + w;
  const int q0L = sL_ * 32, q0H = sH_ * 32;
  const int nkt = qtB + 1;  // 128-key tiles; >= 9, so 2-tile prologue is safe

  // Q fragments for both strips
  const u16* QpL = Qh + (long)(q0L + q5) * 64 + hi * 8;
  bf16x8 qfL0 = *(const bf16x8*)(QpL);
  bf16x8 qfL1 = *(const bf16x8*)(QpL + 16);
  bf16x8 qfL2 = *(const bf16x8*)(QpL + 32);
  bf16x8 qfL3 = *(const bf16x8*)(QpL + 48);
  const u16* QpH = Qh + (long)(q0H + q5) * 64 + hi * 8;
  bf16x8 qfH0 = *(const bf16x8*)(QpH);
  bf16x8 qfH1 = *(const bf16x8*)(QpH + 16);
  bf16x8 qfH2 = *(const bf16x8*)(QpH + 32);
  bf16x8 qfH3 = *(const bf16x8*)(QpH + 48);

  f32x16 aL0, aL1, aH0, aH1;
#pragma unroll
  for (int r = 0; r < 16; ++r) { aL0[r] = 0.f; aL1[r] = 0.f; aH0[r] = 0.f; aH1[r] = 0.f; }
  float lL = 0.f, lH = 0.f;

  auto stage = [&](int buf, int kt) {
    const int kbase = kt << 7;   // 128 keys per tile
#pragma unroll
    for (int ps = 0; ps < 4; ++ps) {
      int i = ps * 256 + t;                       // 1024 chunks -> 16KB K
      int r = i >> 3, c = i & 7, cs = c ^ (r & 7);
      async_lds16(sKb + buf * 16384 + i * 16, Kh + (long)(kbase + r) * 64 + cs * 8);
    }
#pragma unroll
    for (int ps = 0; ps < 4; ++ps) {
      int i = ps * 256 + t;                       // 1024 chunks -> 16KB V
      int d = i >> 4, c = i & 15, cs = c ^ (d & 7);
      async_lds16(sVb + buf * 16384 + i * 16, Vh + (long)d * 2048 + kbase + cs * 8);
    }
  };

  stage(0, 0);
  stage(1, 1);
#pragma unroll 1
  for (int kt = 0; kt < nkt; ++kt) {
    if (kt + 1 < nkt) asm volatile("s_waitcnt vmcnt(8)" ::: "memory");
    else              asm volatile("s_waitcnt vmcnt(0)" ::: "memory");
    __builtin_amdgcn_s_barrier();
    __builtin_amdgcn_sched_barrier(0);
    const char* Kt = sKb + (kt & 1) * 16384;
    const char* Vt = sVb + (kt & 1) * 16384;
    const int c4 = 4 * kt;
    // heavy strip (4 sub-blocks per tile)
    if (c4 <= sH_) {
      if (c4 == sH_) attn_sub<true>(Kt, Vt, 0, qfH0, qfH1, qfH2, qfH3, aH0, aH1, lH, q5, hi);
      else           attn_sub<false>(Kt, Vt, 0, qfH0, qfH1, qfH2, qfH3, aH0, aH1, lH, q5, hi);
    }
    if (c4 + 1 <= sH_) {
      if (c4 + 1 == sH_) attn_sub<true>(Kt, Vt, 1, qfH0, qfH1, qfH2, qfH3, aH0, aH1, lH, q5, hi);
      else               attn_sub<false>(Kt, Vt, 1, qfH0, qfH1, qfH2, qfH3, aH0, aH1, lH, q5, hi);
    }
    if (c4 + 2 <= sH_) {
      if (c4 + 2 == sH_) attn_sub<true>(Kt, Vt, 2, qfH0, qfH1, qfH2, qfH3, aH0, aH1, lH, q5, hi);
      else               attn_sub<false>(Kt, Vt, 2, qfH0, qfH1, qfH2, qfH3, aH0, aH1, lH, q5, hi);
    }
    if (c4 + 3 <= sH_) {
      if (c4 + 3 == sH_) attn_sub<true>(Kt, Vt, 3, qfH0, qfH1, qfH2, qfH3, aH0, aH1, lH, q5, hi);
      else               attn_sub<false>(Kt, Vt, 3, qfH0, qfH1, qfH2, qfH3, aH0, aH1, lH, q5, hi);
    }
    // light strip
    if (c4 <= sL_) {
      if (c4 == sL_) attn_sub<true>(Kt, Vt, 0, qfL0, qfL1, qfL2, qfL3, aL0, aL1, lL, q5, hi);
      else           attn_sub<false>(Kt, Vt, 0, qfL0, qfL1, qfL2, qfL3, aL0, aL1, lL, q5, hi);
    }
    if (c4 + 1 <= sL_) {
      if (c4 + 1 == sL_) attn_sub<true>(Kt, Vt, 1, qfL0, qfL1, qfL2, qfL3, aL0, aL1, lL, q5, hi);
      else               attn_sub<false>(Kt, Vt, 1, qfL0, qfL1, qfL2, qfL3, aL0, aL1, lL, q5, hi);
    }
    if (c4 + 2 <= sL_) {
      if (c4 + 2 == sL_) attn_sub<true>(Kt, Vt, 2, qfL0, qfL1, qfL2, qfL3, aL0, aL1, lL, q5, hi);
      else               attn_sub<false>(Kt, Vt, 2, qfL0, qfL1, qfL2, qfL3, aL0, aL1, lL, q5, hi);
    }
    if (c4 + 3 <= sL_) {
      if (c4 + 3 == sL_) attn_sub<true>(Kt, Vt, 3, qfL0, qfL1, qfL2, qfL3, aL0, aL1, lL, q5, hi);
      else               attn_sub<false>(Kt, Vt, 3, qfL0, qfL1, qfL2, qfL3, aL0, aL1, lL, q5, hi);
    }
    __builtin_amdgcn_sched_barrier(0);
    __builtin_amdgcn_s_barrier();
    if (kt + 2 < nkt) stage(kt & 1, kt + 2);
  }

  // epilogues (no LDS use)
  const long orow_base = (long)b * 2048;
  lH += __shfl_xor(lH, 32);
  float liH = 1.0f / lH;
#pragma unroll
  for (int r = 0; r < 16; ++r) {
    int crow = (r & 3) + 8 * (r >> 2) + 4 * hi;
    float lf = __shfl(liH, crow);
    long orow = orow_base + q0H + crow;
    Og[orow * 1024 + h * 64 + q5] = f2bf(aH0[r] * lf);
    Og[orow * 1024 + h * 64 + 32 + q5] = f2bf(aH1[r] * lf);
  }
  lL += __shfl_xor(lL, 32);
  float liL = 1.0f / lL;
#pragma unroll
  for (int r = 0; r < 16; ++r) {
    int crow = (r & 3) + 8 * (r >> 2) + 4 * hi;
    float lf = __shfl(liL, crow);
    long orow = orow_base + q0L + crow;
    Og[orow * 1024 + h * 64 + q5] = f2bf(aL0[r] * lf);
    Og[orow * 1024 + h * 64 + 32 + q5] = f2bf(aL1[r] * lf);
  }
}

// ---------------- launch ----------------

extern "C" void kernel_launch(void* const* d_in, const int* in_sizes, int n_in,
                              void* d_out, int out_size, void* d_ws, size_t ws_size,
                              hipStream_t stream) {
  const float* x = (const float*)d_in[0];
  const float* w_qkv = (const float*)d_in[1];
  const float* w_out = (const float*)d_in[2];
  float* out = (float*)d_out;
  char* ws = (char*)d_ws;

  u16* xb    = (u16*)(ws + 0);          // 8 MB, reused as Ob after attention
  u16* wqkvT = (u16*)(ws + 8388608L);   // 6 MB
  u16* woutT = (u16*)(ws + 14680064L);  // 2 MB
  u16* Qb    = (u16*)(ws + 16777216L);  // 8 MB
  u16* Kb    = (u16*)(ws + 25165824L);  // 8 MB
  u16* Vt    = (u16*)(ws + 33554432L);  // 8 MB (written transposed by GEMM1)
  u16* Ob    = xb;                      // alias: xb dead after GEMM1

  k_prep<<<dim3(8192), 256, 0, stream>>>(x, xb, w_qkv, wqkvT, w_out, woutT);
  k_gemm_qkv<<<dim3(256), 512, 0, stream>>>(xb, wqkvT, Qb, Kb, Vt);
  k_attn<<<dim3(256), 256, 0, stream>>>(Qb, Kb, Vt, Ob);
  k_gemm_out<<<dim3(256), 256, 0, stream>>>(Ob, woutT, out);
}

// Round 25
// 102.646 us; speedup vs baseline: 1.1046x; 1.0033x over previous
//
#include <hip/hip_runtime.h>

typedef unsigned short u16;
typedef unsigned int u32;
typedef __attribute__((ext_vector_type(8))) short bf16x8;
typedef __attribute__((ext_vector_type(4))) float f32x4;
typedef __attribute__((ext_vector_type(16))) float f32x16;
typedef __attribute__((ext_vector_type(4))) u32 u32x4;

#define MFMA16(a, b, c) __builtin_amdgcn_mfma_f32_16x16x32_bf16((a), (b), (c), 0, 0, 0)
#define MFMA32(a, b, c) __builtin_amdgcn_mfma_f32_32x32x16_bf16((a), (b), (c), 0, 0, 0)

__device__ __forceinline__ void async_lds16(void* lds, const void* g) {
  __builtin_amdgcn_global_load_lds(
      (const __attribute__((address_space(1))) void*)g,
      (__attribute__((address_space(3))) void*)lds, 16, 0, 0);
}

__device__ __forceinline__ u16 f2bf(float f) {
  union { float f; unsigned u; } v; v.f = f;
  unsigned r = v.u + 0x7fffu + ((v.u >> 16) & 1u);
  return (u16)(r >> 16);
}

__device__ __forceinline__ u32 cvt_pk_bf16(float lo, float hi) {
  u32 r;
  asm("v_cvt_pk_bf16_f32 %0, %1, %2" : "=v"(r) : "v"(lo), "v"(hi));
  return r;
}

__device__ __forceinline__ float exp2_fast(float x) {
  float r;
  asm("v_exp_f32 %0, %1" : "=v"(r) : "v"(x));
  return r;
}

// swaps a's hi-32 lanes with b's lo-32 lanes
__device__ __forceinline__ void pswap(u32& a, u32& b) {
  asm("v_permlane32_swap_b32 %0, %1" : "+v"(a), "+v"(b));
}

// ---------------- fused preprocess kernel ----------------
// blocks [0,4096): f32->bf16 cvt of x; [4096,7168): w_qkv transpose (96x32);
// [7168,8192): w_out transpose (32x32).

__device__ __forceinline__ void transpose_cvt_body(const float* __restrict__ in, u16* __restrict__ out,
                                                   int R, int C, int bx, int by,
                                                   float (*tile)[33]) {
  int c0 = bx * 32, r0 = by * 32;
  int tx = threadIdx.x & 31, ty = threadIdx.x >> 5;
#pragma unroll
  for (int i = 0; i < 32; i += 8)
    tile[ty + i][tx] = in[(long)(r0 + ty + i) * C + c0 + tx];
  __syncthreads();
#pragma unroll
  for (int i = 0; i < 32; i += 8)
    out[(long)(c0 + ty + i) * R + r0 + tx] = f2bf(tile[tx][ty + i]);
}

__global__ __launch_bounds__(256) void k_prep(const float* __restrict__ x, u16* __restrict__ xb,
                                              const float* __restrict__ w_qkv, u16* __restrict__ wqkvT,
                                              const float* __restrict__ w_out, u16* __restrict__ woutT) {
  __shared__ float tile[32][33];
  const int B = blockIdx.x;
  if (B < 4096) {
    int i = (B * 256 + threadIdx.x) * 4;
    float4 v = *(const float4*)(x + i);
    ushort4 o;
    o.x = f2bf(v.x); o.y = f2bf(v.y); o.z = f2bf(v.z); o.w = f2bf(v.w);
    *(ushort4*)(xb + i) = o;
  } else if (B < 7168) {
    int bb = B - 4096;
    transpose_cvt_body(w_qkv, wqkvT, 1024, 3072, bb % 96, bb / 96, tile);
  } else {
    int bb = B - 7168;
    transpose_cvt_body(w_out, woutT, 1024, 1024, bb & 31, bb >> 5, tile);
  }
}

// ---------------- NT GEMM core (counted-vmcnt single-barrier pipeline) ----------------

template <int BM, int BN, int NW, int WN, int WCS, int MR, int NR, int NLD>
__device__ __forceinline__ void gemm_core_pipe(const u16* __restrict__ A, const u16* __restrict__ Bt,
                                               int K, long row0, long col0,
                                               u16* sA, u16* sB, f32x4 (&acc)[MR][NR]) {
  const int NTHR = NW * 64;
  const int ABYTES = BM * 64 * 2;
  const int BBYTES = BN * 64 * 2;
  const int t = threadIdx.x;
  const int lane = t & 63, g = lane >> 4, m16 = lane & 15;
  const int wid = t >> 6, wr = wid / WN, wc = wid % WN;
  const int nkt = K >> 6;

  auto stage = [&](int buf, int kt) {
    const int k0 = kt << 6;
#pragma unroll
    for (int it = 0; it < ABYTES / (NTHR * 16); ++it) {
      int i = it * NTHR + t;
      int r = i >> 3, c = i & 7, cs = c ^ (r & 7);
      async_lds16((char*)sA + buf * ABYTES + i * 16, A + (row0 + r) * K + k0 + cs * 8);
    }
#pragma unroll
    for (int it = 0; it < BBYTES / (NTHR * 16); ++it) {
      int i = it * NTHR + t;
      int r = i >> 3, c = i & 7, cs = c ^ (r & 7);
      async_lds16((char*)sB + buf * BBYTES + i * 16, Bt + (col0 + r) * K + k0 + cs * 8);
    }
  };

  stage(0, 0);
  stage(1, 1);
  int cur = 0;
  for (int kt = 0; kt < nkt; ++kt) {
    if (kt + 1 < nkt) {
      if constexpr (NLD == 7) asm volatile("s_waitcnt vmcnt(7)" ::: "memory");
      else                    asm volatile("s_waitcnt vmcnt(8)" ::: "memory");
    } else {
      asm volatile("s_waitcnt vmcnt(0)" ::: "memory");
    }
    __builtin_amdgcn_s_barrier();
    __builtin_amdgcn_sched_barrier(0);
    const char* bA = (const char*)sA + cur * ABYTES;
    const char* bB = (const char*)sB + cur * BBYTES;
#pragma unroll
    for (int kk6 = 0; kk6 < 2; ++kk6) {
      const int ke = kk6 * 32 + 8 * g;
      bf16x8 av[MR], bv[NR];
#pragma unroll
      for (int mi = 0; mi < MR; ++mi) {
        int row = wr * (MR * 16) + mi * 16 + m16;
        av[mi] = *(const bf16x8*)(bA + (row << 7) + ((ke << 1) ^ ((row & 7) << 4)));
      }
#pragma unroll
      for (int ni = 0; ni < NR; ++ni) {
        int row = wc * WCS + ni * 16 + m16;
        bv[ni] = *(const bf16x8*)(bB + (row << 7) + ((ke << 1) ^ ((row & 7) << 4)));
      }
#pragma unroll
      for (int mi = 0; mi < MR; ++mi)
#pragma unroll
        for (int ni = 0; ni < NR; ++ni)
          acc[mi][ni] = MFMA16(av[mi], bv[ni], acc[mi][ni]);
    }
    __builtin_amdgcn_sched_barrier(0);
    __builtin_amdgcn_s_barrier();
    if (kt + 2 < nkt) stage(cur, kt + 2);
    cur ^= 1;
  }
}

// GEMM1: xb[4096][1024] x wqkvT[3072][1024]^T, 256x192 tile, 512 thr (8 waves 2x4).
// Grid 256 = 1 block/CU; col0 = colt*192 -> block maps to head colt.
// V is written DIRECTLY in transposed layout Vt[bh][d][s].
__global__ __launch_bounds__(512, 2) void k_gemm_qkv(const u16* __restrict__ xb, const u16* __restrict__ wT,
                                                     u16* __restrict__ Qo, u16* __restrict__ Ko,
                                                     u16* __restrict__ Vt) {
  __shared__ __align__(16) u16 sA[2 * 256 * 64];  // 64KB
  __shared__ __align__(16) u16 sB[2 * 192 * 64];  // 48KB
  f32x4 acc[8][3];
  const f32x4 z = {0.f, 0.f, 0.f, 0.f};
#pragma unroll
  for (int mi = 0; mi < 8; ++mi)
#pragma unroll
    for (int ni = 0; ni < 3; ++ni) acc[mi][ni] = z;
  const int L = blockIdx.x;
  const int xcd = L & 7, idx = L >> 3;          // idx 0..31
  const int rowt = xcd * 2 + (idx & 1);         // 0..15
  const int colt = idx >> 1;                    // 0..15 (= head h)
  long row0 = (long)rowt * 256, col0 = (long)colt * 192;
  gemm_core_pipe<256, 192, 8, 4, 48, 8, 3, 7>(xb, wT, 1024, row0, col0, sA, sB, acc);
  const int t = threadIdx.x;
  const int lane = t & 63, g = lane >> 4, m16 = lane & 15;
  const int wid = t >> 6, wr = wid >> 2, wc = wid & 3;
  const int h = colt;
#pragma unroll
  for (int mi = 0; mi < 8; ++mi) {
#pragma unroll
    for (int ni = 0; ni < 3; ++ni) {
      int rem = wc * 48 + ni * 16 + m16;        // 0..191 within head
      int which = rem >> 6, d = rem & 63;
      int row_base = (int)row0 + wr * 128 + mi * 16 + 4 * g;  // multiple of 4
      int b = row_base >> 11, s = row_base & 2047;
      if (which == 2) {
        // Vt[bh][d][s..s+3]: contiguous, 8B-aligned
        ushort4 o;
        o.x = f2bf(acc[mi][ni][0]); o.y = f2bf(acc[mi][ni][1]);
        o.z = f2bf(acc[mi][ni][2]); o.w = f2bf(acc[mi][ni][3]);
        *(ushort4*)(Vt + ((long)(b * 16 + h)) * 131072 + (long)d * 2048 + s) = o;
      } else {
        long off = (((long)(b * 16 + h)) * 2048 + s) * 64 + d;
#pragma unroll
        for (int r = 0; r < 4; ++r) {
          float v = acc[mi][ni][r];
          if (which == 0) Qo[off + (long)r * 64] = f2bf(v * 0.18033688f);  // 0.125*log2e
          else            Ko[off + (long)r * 64] = f2bf(v);
        }
      }
    }
  }
}

// GEMM2: Ob[4096][1024] x woutT[1024][1024]^T -> out f32 [4096][1024]
__global__ __launch_bounds__(256) void k_gemm_out(const u16* __restrict__ Ob, const u16* __restrict__ wT,
                                                  float* __restrict__ out) {
  __shared__ __align__(16) u16 sA[2 * 128 * 64];  // 32KB
  __shared__ __align__(16) u16 sB[2 * 128 * 64];  // 32KB
  f32x4 acc[4][4];
  const f32x4 z = {0.f, 0.f, 0.f, 0.f};
#pragma unroll
  for (int mi = 0; mi < 4; ++mi)
#pragma unroll
    for (int ni = 0; ni < 4; ++ni) acc[mi][ni] = z;
  const int L = blockIdx.x;
  const int xcd = L & 7, idx = L >> 3;          // idx 0..31
  const int rowt = xcd * 4 + (idx & 3);         // 0..31
  const int colt = idx >> 2;                    // 0..7
  long row0 = (long)rowt * 128, col0 = (long)colt * 128;
  gemm_core_pipe<128, 128, 4, 2, 64, 4, 4, 8>(Ob, wT, 1024, row0, col0, sA, sB, acc);
  const int t = threadIdx.x;
  const int lane = t & 63, g = lane >> 4, m16 = lane & 15;
  const int wid = t >> 6, wr = wid >> 1, wc = wid & 1;
#pragma unroll
  for (int mi = 0; mi < 4; ++mi) {
#pragma unroll
    for (int ni = 0; ni < 4; ++ni) {
#pragma unroll
      for (int r = 0; r < 4; ++r) {
        long row = row0 + wr * 64 + mi * 16 + 4 * g + r;
        long col = col0 + wc * 64 + ni * 16 + m16;
        out[row * 1024 + col] = acc[mi][ni][r];
      }
    }
  }
}

// ---------------- causal flash attention: KVBLK=256 tiles (8 subs/tile), 2-deep ----------------
// Block (bh, pr) = 256 thr = 4 waves; wave w owns heavy strip qtB*4+w and light
// strip qtA*4+w. Tile = 256 keys: K tile 32KB [key][d], V tile 32KB [d][key=256]
// (row stride 512B), both XOR-swizzled, double-buffered (128KB total, 1 block/CU).
// Same pipeline shape as the green GEMM: vmcnt(16)/vmcnt(0), two barriers per tile,
// stage(kt+2) after the second barrier. nkt = ceil((qtB+1)/2) in [5,8].

template <bool DIAG>
__device__ __forceinline__ void attn_sub(const char* Kt, const char* Vt, int bsub,
                                         bf16x8 qf0, bf16x8 qf1, bf16x8 qf2, bf16x8 qf3,
                                         f32x16& acc0, f32x16& acc1, float& l,
                                         int q5, int hi) {
  const int x7 = q5 & 7;
  const int rowK = (bsub * 32 + q5) << 7;          // K row stride 128B (64 d)
  bf16x8 k0 = *(const bf16x8*)(Kt + rowK + (((0 + hi) ^ x7) << 4));
  bf16x8 k1 = *(const bf16x8*)(Kt + rowK + (((2 + hi) ^ x7) << 4));
  bf16x8 k2 = *(const bf16x8*)(Kt + rowK + (((4 + hi) ^ x7) << 4));
  bf16x8 k3 = *(const bf16x8*)(Kt + rowK + (((6 + hi) ^ x7) << 4));
  const int rowV0 = q5 << 9, rowV1 = (q5 + 32) << 9;  // V row stride 512B (256 keys)
  bf16x8 v00 = *(const bf16x8*)(Vt + rowV0 + (((bsub * 4 + 0 + hi) ^ x7) << 4));
  bf16x8 v01 = *(const bf16x8*)(Vt + rowV1 + (((bsub * 4 + 0 + hi) ^ x7) << 4));
  bf16x8 v10 = *(const bf16x8*)(Vt + rowV0 + (((bsub * 4 + 2 + hi) ^ x7) << 4));
  bf16x8 v11 = *(const bf16x8*)(Vt + rowV1 + (((bsub * 4 + 2 + hi) ^ x7) << 4));

  f32x16 s;
#pragma unroll
  for (int r = 0; r < 16; ++r) s[r] = 0.f;
  __builtin_amdgcn_s_setprio(1);
  s = MFMA32(k0, qf0, s);
  s = MFMA32(k1, qf1, s);
  s = MFMA32(k2, qf2, s);
  s = MFMA32(k3, qf3, s);
  __builtin_amdgcn_s_setprio(0);

  float p[16];
#pragma unroll
  for (int r = 0; r < 16; ++r) {
    float pv = exp2_fast(s[r]);
    if (DIAG) {
      int crow = (r & 3) + 8 * (r >> 2) + 4 * hi;
      pv = (crow <= q5) ? pv : 0.f;
    }
    p[r] = pv;
  }
  l += (((p[0] + p[1]) + (p[2] + p[3])) + ((p[4] + p[5]) + (p[6] + p[7]))) +
       (((p[8] + p[9]) + (p[10] + p[11])) + ((p[12] + p[13]) + (p[14] + p[15])));

  u32 a0 = cvt_pk_bf16(p[0], p[1]), a1 = cvt_pk_bf16(p[2], p[3]);
  u32 b0 = cvt_pk_bf16(p[4], p[5]), b1 = cvt_pk_bf16(p[6], p[7]);
  pswap(a0, b0); pswap(a1, b1);
  u32 c0 = cvt_pk_bf16(p[8], p[9]), c1 = cvt_pk_bf16(p[10], p[11]);
  u32 d0 = cvt_pk_bf16(p[12], p[13]), d1 = cvt_pk_bf16(p[14], p[15]);
  pswap(c0, d0); pswap(c1, d1);
  u32x4 t0; t0[0] = a0; t0[1] = a1; t0[2] = b0; t0[3] = b1;
  u32x4 t1; t1[0] = c0; t1[1] = c1; t1[2] = d0; t1[3] = d1;
  bf16x8 pa0 = __builtin_bit_cast(bf16x8, t0);  // keys +0..15, k-slot order
  bf16x8 pa1 = __builtin_bit_cast(bf16x8, t1);  // keys +16..31

  __builtin_amdgcn_s_setprio(1);
  acc0 = MFMA32(pa0, v00, acc0);
  acc1 = MFMA32(pa0, v01, acc1);
  acc0 = MFMA32(pa1, v10, acc0);
  acc1 = MFMA32(pa1, v11, acc1);
  __builtin_amdgcn_s_setprio(0);
}

// Q,K: [32 bh][2048][64] bf16 (Q pre-scaled by 0.125*log2e); Vt: [32 bh][64][2048] bf16
__global__ __launch_bounds__(256) void k_attn(const u16* __restrict__ Qg, const u16* __restrict__ Kg,
                                              const u16* __restrict__ Vtg, u16* __restrict__ Og) {
  __shared__ __align__(16) u16 sK[2][256 * 64];  // [key][d] swizzled, 32KB per buffer
  __shared__ __align__(16) u16 sV[2][64 * 256];  // [d][key] swizzled, 32KB per buffer
  const int t = threadIdx.x;
  const int lane = t & 63, q5 = lane & 31, hi = lane >> 5, w = t >> 6;
  const int L = blockIdx.x;
  const int bh = L & 31, pr = L >> 5;           // XCD affinity: L%8 == bh%8; pr 0..7
  const int qtA = pr, qtB = 15 - pr;
  const int b = bh >> 4, h = bh & 15;
  const u16* Qh = Qg + (long)bh * 131072;
  const u16* Kh = Kg + (long)bh * 131072;
  const u16* Vh = Vtg + (long)bh * 131072;
  char* sKb = (char*)sK;
  char* sVb = (char*)sV;

  const int sL_ = qtA * 4 + w, sH_ = qtB * 4 + w;
  const int q0L = sL_ * 32, q0H = sH_ * 32;
  const int nkt = (qtB + 2) >> 1;  // 256-key tiles; >= 5, so 2-tile prologue is safe

  // Q fragments for both strips
  const u16* QpL = Qh + (long)(q0L + q5) * 64 + hi * 8;
  bf16x8 qfL0 = *(const bf16x8*)(QpL);
  bf16x8 qfL1 = *(const bf16x8*)(QpL + 16);
  bf16x8 qfL2 = *(const bf16x8*)(QpL + 32);
  bf16x8 qfL3 = *(const bf16x8*)(QpL + 48);
  const u16* QpH = Qh + (long)(q0H + q5) * 64 + hi * 8;
  bf16x8 qfH0 = *(const bf16x8*)(QpH);
  bf16x8 qfH1 = *(const bf16x8*)(QpH + 16);
  bf16x8 qfH2 = *(const bf16x8*)(QpH + 32);
  bf16x8 qfH3 = *(const bf16x8*)(QpH + 48);

  f32x16 aL0, aL1, aH0, aH1;
#pragma unroll
  for (int r = 0; r < 16; ++r) { aL0[r] = 0.f; aL1[r] = 0.f; aH0[r] = 0.f; aH1[r] = 0.f; }
  float lL = 0.f, lH = 0.f;

  auto stage = [&](int buf, int kt) {
    const int kbase = kt << 8;   // 256 keys per tile
#pragma unroll
    for (int ps = 0; ps < 8; ++ps) {
      int i = ps * 256 + t;                       // 2048 chunks -> 32KB K
      int r = i >> 3, c = i & 7, cs = c ^ (r & 7);
      async_lds16(sKb + buf * 32768 + i * 16, Kh + (long)(kbase + r) * 64 + cs * 8);
    }
#pragma unroll
    for (int ps = 0; ps < 8; ++ps) {
      int i = ps * 256 + t;                       // 2048 chunks -> 32KB V
      int d = i >> 5, c = i & 31, cs = c ^ (d & 7);
      async_lds16(sVb + buf * 32768 + i * 16, Vh + (long)d * 2048 + kbase + cs * 8);
    }
  };

  stage(0, 0);
  stage(1, 1);
#pragma unroll 1
  for (int kt = 0; kt < nkt; ++kt) {
    if (kt + 1 < nkt) asm volatile("s_waitcnt vmcnt(16)" ::: "memory");
    else              asm volatile("s_waitcnt vmcnt(0)" ::: "memory");
    __builtin_amdgcn_s_barrier();
    __builtin_amdgcn_sched_barrier(0);
    const char* Kt = sKb + (kt & 1) * 32768;
    const char* Vt = sVb + (kt & 1) * 32768;
    const int c8 = 8 * kt;
    // heavy strip (8 sub-blocks per tile)
#pragma unroll
    for (int j = 0; j < 8; ++j) {
      if (c8 + j <= sH_) {
        if (c8 + j == sH_) attn_sub<true>(Kt, Vt, j, qfH0, qfH1, qfH2, qfH3, aH0, aH1, lH, q5, hi);
        else               attn_sub<false>(Kt, Vt, j, qfH0, qfH1, qfH2, qfH3, aH0, aH1, lH, q5, hi);
      }
    }
    // light strip
#pragma unroll
    for (int j = 0; j < 8; ++j) {
      if (c8 + j <= sL_) {
        if (c8 + j == sL_) attn_sub<true>(Kt, Vt, j, qfL0, qfL1, qfL2, qfL3, aL0, aL1, lL, q5, hi);
        else               attn_sub<false>(Kt, Vt, j, qfL0, qfL1, qfL2, qfL3, aL0, aL1, lL, q5, hi);
      }
    }
    __builtin_amdgcn_sched_barrier(0);
    __builtin_amdgcn_s_barrier();
    if (kt + 2 < nkt) stage(kt & 1, kt + 2);
  }

  // epilogues (no LDS use)
  const long orow_base = (long)b * 2048;
  lH += __shfl_xor(lH, 32);
  float liH = 1.0f / lH;
#pragma unroll
  for (int r = 0; r < 16; ++r) {
    int crow = (r & 3) + 8 * (r >> 2) + 4 * hi;
    float lf = __shfl(liH, crow);
    long orow = orow_base + q0H + crow;
    Og[orow * 1024 + h * 64 + q5] = f2bf(aH0[r] * lf);
    Og[orow * 1024 + h * 64 + 32 + q5] = f2bf(aH1[r] * lf);
  }
  lL += __shfl_xor(lL, 32);
  float liL = 1.0f / lL;
#pragma unroll
  for (int r = 0; r < 16; ++r) {
    int crow = (r & 3) + 8 * (r >> 2) + 4 * hi;
    float lf = __shfl(liL, crow);
    long orow = orow_base + q0L + crow;
    Og[orow * 1024 + h * 64 + q5] = f2bf(aL0[r] * lf);
    Og[orow * 1024 + h * 64 + 32 + q5] = f2bf(aL1[r] * lf);
  }
}

// ---------------- launch ----------------

extern "C" void kernel_launch(void* const* d_in, const int* in_sizes, int n_in,
                              void* d_out, int out_size, void* d_ws, size_t ws_size,
                              hipStream_t stream) {
  const float* x = (const float*)d_in[0];
  const float* w_qkv = (const float*)d_in[1];
  const float* w_out = (const float*)d_in[2];
  float* out = (float*)d_out;
  char* ws = (char*)d_ws;

  u16* xb    = (u16*)(ws + 0);          // 8 MB, reused as Ob after attention
  u16* wqkvT = (u16*)(ws + 8388608L);   // 6 MB
  u16* woutT = (u16*)(ws + 14680064L);  // 2 MB
  u16* Qb    = (u16*)(ws + 16777216L);  // 8 MB
  u16* Kb    = (u16*)(ws + 25165824L);  // 8 MB
  u16* Vt    = (u16*)(ws + 33554432L);  // 8 MB (written transposed by GEMM1)
  u16* Ob    = xb;                      // alias: xb dead after GEMM1

  k_prep<<<dim3(8192), 256, 0, stream>>>(x, xb, w_qkv, wqkvT, w_out, woutT);
  k_gemm_qkv<<<dim3(256), 512, 0, stream>>>(xb, wqkvT, Qb, Kb, Vt);
  k_attn<<<dim3(256), 256, 0, stream>>>(Qb, Kb, Vt, Ob);
  k_gemm_out<<<dim3(256), 256, 0, stream>>>(Ob, woutT, out);
}